// Round 5
// baseline (158.366 us; speedup 1.0000x reference)
//
#include <hip/hip_runtime.h>

#define D_IN   2048
#define D_OUT  2048
#define N_TOK  1024
#define N_B    8
#define RANK   16
#define KSPLIT 2
#define KHALF  (D_IN / KSPLIT)   // 1024
// SCALING = ALPHA/RANK = 1.0 -> omitted
// ws usage: float W[KSPLIT][N_B][N_TOK][RANK] = 1 MB fp32 partials

__device__ __forceinline__ float dot4(float4 a, float4 b) {
    return a.x * b.x + a.y * b.y + a.z * b.z + a.w * b.w;
}

__device__ __forceinline__ float4 f4add(float4 a, float4 b) {
    return make_float4(a.x + b.x, a.y + b.y, a.z + b.z, a.w + b.w);
}

template <int CTRL>
__device__ __forceinline__ float dpp_add(float v) {
    int s = __builtin_amdgcn_update_dpp(0, __float_as_int(v), CTRL, 0xF, 0xF, true);
    return v + __int_as_float(s);
}

// 64-lane sum: 4 DPP steps (VALU pipe) + 2 shuffles. Verified R2-R4.
__device__ __forceinline__ float wave_sum(float v) {
    v = dpp_add<0xB1>(v);    // quad_perm [1,0,3,2]
    v = dpp_add<0x4E>(v);    // quad_perm [2,3,0,1]
    v = dpp_add<0x124>(v);   // row_ror:4
    v = dpp_add<0x128>(v);   // row_ror:8
    v += __shfl_xor(v, 16, 64);
    v += __shfl_xor(v, 32, 64);
    return v;
}

// NOTE (R2/R3 post-mortem): hipcc maps __launch_bounds__(256,4) -> 64-VGPR cap
// and spills ~500 MB. (256,2) -> 128 cap, no spill. Use (256,2) everywhere.

// ---------- K1: W[ks][b][t][r] = sum_{i in K-half} x[b,t,i] * B[a,r,i] ----------
__global__ __launch_bounds__(256, 2)
void lora_bx(const float* __restrict__ x,
             const float* __restrict__ B,
             const int* __restrict__ ids,
             float* __restrict__ W) {
    const int tile = blockIdx.x;          // 8-token tile
    const int ks   = blockIdx.y;          // K-split index
    const int b    = blockIdx.z;
    const int aid  = ids[b];
    const int wave = (int)(threadIdx.x >> 6);   // wave owns tokens t0, t0+1
    const int lane = (int)(threadIdx.x & 63);
    const int t0   = tile * 8 + wave * 2;

    const float* __restrict__ xb = x + ((size_t)b * N_TOK + t0) * D_IN + ks * KHALF;
    const float* __restrict__ Ba = B + (size_t)aid * RANK * D_IN + ks * KHALF;

    float acc0[RANK], acc1[RANK];
    #pragma unroll
    for (int r = 0; r < RANK; ++r) { acc0[r] = 0.f; acc1[r] = 0.f; }

    #pragma unroll
    for (int chunk = 0; chunk < KHALF / 256; ++chunk) {   // 4 chunks
        const int ib = chunk * 256 + lane * 4;
        const float4 xv0 = *reinterpret_cast<const float4*>(&xb[ib]);
        const float4 xv1 = *reinterpret_cast<const float4*>(&xb[D_IN + ib]);
        // ranks in 4 subgroups of 4 -> small live set (~75 VGPR total)
        #pragma unroll
        for (int g = 0; g < 4; ++g) {
            float4 Bv[4];
            #pragma unroll
            for (int r = 0; r < 4; ++r)
                Bv[r] = *reinterpret_cast<const float4*>(&Ba[(size_t)(g * 4 + r) * D_IN + ib]);
            #pragma unroll
            for (int r = 0; r < 4; ++r) {
                acc0[g * 4 + r] += dot4(xv0, Bv[r]);
                acc1[g * 4 + r] += dot4(xv1, Bv[r]);
            }
        }
    }

    #pragma unroll
    for (int r = 0; r < RANK; ++r) {
        acc0[r] = wave_sum(acc0[r]);
        acc1[r] = wave_sum(acc1[r]);
    }

    if (lane == 0) {
        float* Wp = W + (((size_t)ks * N_B + b) * N_TOK + t0) * RANK;
        *reinterpret_cast<float4*>(&Wp[0])         = make_float4(acc0[0],  acc0[1],  acc0[2],  acc0[3]);
        *reinterpret_cast<float4*>(&Wp[4])         = make_float4(acc0[4],  acc0[5],  acc0[6],  acc0[7]);
        *reinterpret_cast<float4*>(&Wp[8])         = make_float4(acc0[8],  acc0[9],  acc0[10], acc0[11]);
        *reinterpret_cast<float4*>(&Wp[12])        = make_float4(acc0[12], acc0[13], acc0[14], acc0[15]);
        *reinterpret_cast<float4*>(&Wp[RANK + 0])  = make_float4(acc1[0],  acc1[1],  acc1[2],  acc1[3]);
        *reinterpret_cast<float4*>(&Wp[RANK + 4])  = make_float4(acc1[4],  acc1[5],  acc1[6],  acc1[7]);
        *reinterpret_cast<float4*>(&Wp[RANK + 8])  = make_float4(acc1[8],  acc1[9],  acc1[10], acc1[11]);
        *reinterpret_cast<float4*>(&Wp[RANK + 12]) = make_float4(acc1[12], acc1[13], acc1[14], acc1[15]);
    }
}

// ---------- K2: out[b,t,o] = sum_r (W[0][b][t][r] + W[1][b][t][r]) * A[a,o,r] ----------
__global__ __launch_bounds__(256, 2)
void lora_out(const float* __restrict__ A,
              const int* __restrict__ ids,
              const float* __restrict__ W,
              float* __restrict__ out) {
    const int tile = blockIdx.x;          // 8-token tile
    const int half = blockIdx.y;          // o-half
    const int b    = blockIdx.z;
    const int aid  = ids[b];
    const int o0   = half * 1024 + (int)threadIdx.x * 4;

    const float* __restrict__ Aa  = A + (size_t)aid * D_OUT * RANK;
    const float* __restrict__ Wb0 = W + ((size_t)b * N_TOK + tile * 8) * RANK;                      // ks=0
    const float* __restrict__ Wb1 = W + (((size_t)N_B + b) * N_TOK + tile * 8) * RANK;              // ks=1
    float* __restrict__ ob = out + ((size_t)b * N_TOK + tile * 8) * D_OUT;

    float4 Ar[4][4];
    #pragma unroll
    for (int j = 0; j < 4; ++j)
        #pragma unroll
        for (int q = 0; q < 4; ++q)
            Ar[j][q] = *reinterpret_cast<const float4*>(&Aa[(size_t)(o0 + j) * RANK + q * 4]);

    #pragma unroll
    for (int t = 0; t < 8; ++t) {
        const float4 p0 = f4add(*reinterpret_cast<const float4*>(&Wb0[t * RANK + 0]),
                                *reinterpret_cast<const float4*>(&Wb1[t * RANK + 0]));
        const float4 p1 = f4add(*reinterpret_cast<const float4*>(&Wb0[t * RANK + 4]),
                                *reinterpret_cast<const float4*>(&Wb1[t * RANK + 4]));
        const float4 p2 = f4add(*reinterpret_cast<const float4*>(&Wb0[t * RANK + 8]),
                                *reinterpret_cast<const float4*>(&Wb1[t * RANK + 8]));
        const float4 p3 = f4add(*reinterpret_cast<const float4*>(&Wb0[t * RANK + 12]),
                                *reinterpret_cast<const float4*>(&Wb1[t * RANK + 12]));
        float4 res;
        res.x = dot4(Ar[0][0], p0) + dot4(Ar[0][1], p1) + dot4(Ar[0][2], p2) + dot4(Ar[0][3], p3);
        res.y = dot4(Ar[1][0], p0) + dot4(Ar[1][1], p1) + dot4(Ar[1][2], p2) + dot4(Ar[1][3], p3);
        res.z = dot4(Ar[2][0], p0) + dot4(Ar[2][1], p1) + dot4(Ar[2][2], p2) + dot4(Ar[2][3], p3);
        res.w = dot4(Ar[3][0], p0) + dot4(Ar[3][1], p1) + dot4(Ar[3][2], p2) + dot4(Ar[3][3], p3);
        *reinterpret_cast<float4*>(&ob[(size_t)t * D_OUT + o0]) = res;
    }
}

extern "C" void kernel_launch(void* const* d_in, const int* in_sizes, int n_in,
                              void* d_out, int out_size, void* d_ws, size_t ws_size,
                              hipStream_t stream) {
    const float* x   = (const float*)d_in[0];
    const float* A   = (const float*)d_in[1];
    const float* B   = (const float*)d_in[2];
    const int*   ids = (const int*)d_in[3];
    float* out = (float*)d_out;
    float* W   = (float*)d_ws;   // 1 MB: [KSPLIT][N_B][N_TOK][RANK]

    dim3 g1(N_TOK / 8, KSPLIT, N_B);   // (128, 2, 8) = 2048 blocks
    lora_bx<<<g1, 256, 0, stream>>>(x, B, ids, W);

    dim3 g2(N_TOK / 8, 2, N_B);        // (128, 2, 8) = 2048 blocks
    lora_out<<<g2, 256, 0, stream>>>(A, ids, W, out);
}